// Round 9
// baseline (307.931 us; speedup 1.0000x reference)
//
#include <hip/hip_runtime.h>
#include <math.h>

#define H    768
#define NT   24           // H/32 K-tiles
#define DIM  128
#define LQ   32
#define LD   512
#define BM   32           // tokens per block (full-H staged)
#define EPSF 1e-12f

typedef _Float16 f16x8 __attribute__((ext_vector_type(8)));
typedef _Float16 f16x4 __attribute__((ext_vector_type(4)));
typedef float    f32x4 __attribute__((ext_vector_type(4)));

static __device__ __forceinline__ unsigned short h2u(_Float16 h) {
    return __builtin_bit_cast(unsigned short, h);
}

// ------- W -> f16 hi/lo [ks][hi/lo][dim][32] (unswizzled) + WT fp32 ---------
__global__ __launch_bounds__(256) void wconv_kernel(
    const float* __restrict__ W, unsigned short* __restrict__ wsW,
    float* __restrict__ WT)
{
    const int ks  = blockIdx.x;
    const int tid = threadIdx.x;
    #pragma unroll 4
    for (int i = 0; i < 16; ++i) {
        const int idx = tid + i * 256;          // 0..4095
        const int row = idx >> 5, col = idx & 31;   // row=dim, col=k-in-tile
        const float x = W[(size_t)row * H + ks * 32 + col];
        const _Float16 hi = (_Float16)x;
        const _Float16 lo = (_Float16)(x - (float)hi);
        wsW[(((size_t)ks * 2 + 0) * 128 + row) * 32 + col] = h2u(hi);
        wsW[(((size_t)ks * 2 + 1) * 128 + row) * 32 + col] = h2u(lo);
        WT[((size_t)ks * 32 + col) * DIM + row] = x;
    }
}

// ---------------- query projection (coalesced via WT) + L2 norm -> f16 -------
__global__ __launch_bounds__(128) void qproj_kernel(
    const float* __restrict__ qh, const float* __restrict__ WT,
    unsigned short* __restrict__ qn)
{
    const int blk = blockIdx.x;   // 4 tokens per block
    const int tid = threadIdx.x;  // = output dim
    __shared__ float rows[4][H];
    __shared__ float red[128];

    const float4* src = (const float4*)(qh + (size_t)blk * 4 * H);
    float4*       dst = (float4*)&rows[0][0];
    for (int i = tid; i < 4 * H / 4; i += 128) dst[i] = src[i];
    __syncthreads();

    float acc[4] = {0.f, 0.f, 0.f, 0.f};
    #pragma unroll 8
    for (int h = 0; h < H; ++h) {
        const float wv = WT[(size_t)h * DIM + tid];   // coalesced across lanes
        acc[0] += wv * rows[0][h];
        acc[1] += wv * rows[1][h];
        acc[2] += wv * rows[2][h];
        acc[3] += wv * rows[3][h];
    }
    #pragma unroll
    for (int j = 0; j < 4; ++j) {
        red[tid] = acc[j] * acc[j];
        __syncthreads();
        for (int s = 64; s > 0; s >>= 1) {
            if (tid < s) red[tid] += red[tid + s];
            __syncthreads();
        }
        const float inv = 1.0f / fmaxf(sqrtf(red[0]), EPSF);
        qn[((size_t)blk * 4 + j) * DIM + tid] = h2u((_Float16)(acc[j] * inv));
        __syncthreads();
    }
}

// -------- doc: full-H contiguous A staging, W from L2, no K-loop barriers ----
// A_lds[32][768] f16, granule(16B)-XOR-swizzled: byte = row*1536 + ((gr ^ (row&7))*16 + sub)
struct Smem {
    union {
        unsigned short A[BM][H];      // 48 KB (K-loop)
        unsigned short C[BM][DIM];    // 8 KB  (epilogue overlay)
    } u;
    float         pnorm[2][BM];
    unsigned char mk[BM];
    float         pmax[LQ][2];
};

__global__ __launch_bounds__(256, 3) void docgemm_kernel(
    const float* __restrict__ dh, const unsigned short* __restrict__ wsW,
    const int* __restrict__ dmask, const unsigned short* __restrict__ qn,
    float* __restrict__ part, const int* __restrict__ ppq_p)
{
    __shared__ Smem sm;
    const int blk = blockIdx.x;          // 4096 blocks = 131072 tokens / 32
    const int b   = blk >> 4;            // doc
    const int c   = blk & 15;            // 32-token chunk
    const int tid = threadIdx.x;
    const int w   = tid >> 6;            // wave 0..3
    const int m   = w & 1;               // token-tile (16 tokens)
    const int nq  = w >> 1;              // dim-half (64 dims)
    const int l   = tid & 63;
    const int g   = l >> 4;
    const int r15 = l & 15;
    const int ppq = ppq_p[0];

    // ---- stage: 32 rows x 768 fp32, perfectly sequential, -> f16 LDS swizzled
    {
        const float4* gsrc = (const float4*)(dh + (size_t)blk * BM * H);
        char* abase = (char*)&sm.u.A[0][0];
        #pragma unroll 6
        for (int j = 0; j < 24; ++j) {
            const int idx = tid + j * 256;      // float4 index 0..6143
            const float4 v = gsrc[idx];
            const int row = idx / 192;          // 768/4 float4 per row
            const int c4  = idx % 192;
            const int colg = c4 >> 1;           // 16-B granule 0..95
            const int sub  = (c4 & 1) * 4;      // float offset in granule
            f16x4 h;
            h[0] = (_Float16)v.x; h[1] = (_Float16)v.y;
            h[2] = (_Float16)v.z; h[3] = (_Float16)v.w;
            *(f16x4*)(abase + (size_t)row * 1536 + ((colg ^ (row & 7)) * 8 + sub) * 2) = h;
        }
    }
    if (tid < BM) sm.mk[tid] = (unsigned char)(dmask[(size_t)b * LD + c * BM + tid] != 0);
    __syncthreads();

    // ---- K-loop: A from LDS, W hi/lo direct from L2-resident wsW, no barriers
    f32x4 acc[4];
    #pragma unroll
    for (int n = 0; n < 4; ++n) acc[n] = (f32x4){0.f, 0.f, 0.f, 0.f};

    const char* arow = (const char*)&sm.u.A[0][0] + (size_t)(m * 16 + r15) * 1536;
    const int   rsw  = (r15 & 7);
    const unsigned short* wlane = wsW + (size_t)(nq * 64 + r15) * 32 + g * 8;

    #pragma unroll 4
    for (int t = 0; t < NT; ++t) {
        const f16x8 af = *(const f16x8*)(arow + ((t * 4 + g) ^ rsw) * 16);
        const unsigned short* wt = wlane + (size_t)t * 8192;
        __builtin_amdgcn_s_setprio(1);
        #pragma unroll
        for (int n = 0; n < 4; ++n) {
            f16x8 bh = *(const f16x8*)(wt + n * 512);
            f16x8 bl = *(const f16x8*)(wt + 4096 + n * 512);
            acc[n] = __builtin_amdgcn_mfma_f32_16x16x32_f16(af, bh, acc[n], 0, 0, 0);
            acc[n] = __builtin_amdgcn_mfma_f32_16x16x32_f16(af, bl, acc[n], 0, 0, 0);
        }
        __builtin_amdgcn_s_setprio(0);
    }

    __syncthreads();   // all waves done reading A before C overlays it

    // ---- epilogue 1: C f16 (granule-swizzled) + per-token norm partials
    #pragma unroll
    for (int n = 0; n < 4; ++n) {
        const int dim  = nq * 64 + n * 16 + r15;
        #pragma unroll
        for (int r = 0; r < 4; ++r) {
            const int tok  = m * 16 + g * 4 + r;
            const int colg = (dim >> 3) ^ (tok & 7);
            sm.u.C[tok][colg * 8 + (dim & 7)] = h2u((_Float16)acc[n][r]);
        }
    }
    #pragma unroll
    for (int r = 0; r < 4; ++r) {
        float s = 0.f;
        #pragma unroll
        for (int n = 0; n < 4; ++n) s += acc[n][r] * acc[n][r];
        s += __shfl_xor(s, 1); s += __shfl_xor(s, 2);
        s += __shfl_xor(s, 4); s += __shfl_xor(s, 8);
        if (r15 == 0) sm.pnorm[nq][m * 16 + g * 4 + r] = s;
    }
    __syncthreads();

    // ---- epilogue 2: sim [32 q] x [16 tok per wave], K=128; Q f16 from global
    const unsigned short* qb = qn + (size_t)(b / ppq) * LQ * DIM;
    const int qm = w & 1;                // query-tile
    const int tn = w >> 1;               // token-tile
    const int tok = tn * 16 + r15;
    const float inv = 1.0f / fmaxf(sqrtf(sm.pnorm[0][tok] + sm.pnorm[1][tok]), EPSF);
    const int msk = sm.mk[tok];

    f32x4 sacc = (f32x4){0.f, 0.f, 0.f, 0.f};
    #pragma unroll
    for (int ks = 0; ks < 4; ++ks) {
        f16x8 qa = *(const f16x8*)(qb + (size_t)(qm * 16 + r15) * DIM + ks * 32 + g * 8);
        const int colg = (ks * 4 + g) ^ (tok & 7);
        f16x8 cb = *(const f16x8*)&sm.u.C[tok][colg * 8];
        sacc = __builtin_amdgcn_mfma_f32_16x16x32_f16(qa, cb, sacc, 0, 0, 0);
    }

    #pragma unroll
    for (int r = 0; r < 4; ++r) {
        float v = msk ? sacc[r] * inv : -INFINITY;
        v = fmaxf(v, __shfl_xor(v, 1));
        v = fmaxf(v, __shfl_xor(v, 2));
        v = fmaxf(v, __shfl_xor(v, 4));
        v = fmaxf(v, __shfl_xor(v, 8));
        if (r15 == 0) sm.pmax[qm * 16 + g * 4 + r][tn] = v;
    }
    __syncthreads();
    if (tid < LQ)
        part[(size_t)blk * LQ + tid] = fmaxf(sm.pmax[tid][0], sm.pmax[tid][1]);
}

// ---------------- final: max over 16 chunks, sum over 32 queries -------------
__global__ __launch_bounds__(64) void final_kernel(
    const float* __restrict__ part, float* __restrict__ out)
{
    const int b = blockIdx.x;
    const int q = threadIdx.x & 31;
    const int h = threadIdx.x >> 5;          // chunk half
    const float* p = part + (size_t)b * 16 * LQ;
    float m = -INFINITY;
    #pragma unroll
    for (int cchunk = 0; cchunk < 8; ++cchunk)
        m = fmaxf(m, p[(h * 8 + cchunk) * LQ + q]);
    m = fmaxf(m, __shfl_xor(m, 32));
    if (threadIdx.x < 32) {
        #pragma unroll
        for (int off = 1; off < 32; off <<= 1) m += __shfl_xor(m, off);
        if (threadIdx.x == 0) out[b] = m;
    }
}

extern "C" void kernel_launch(void* const* d_in, const int* in_sizes, int n_in,
                              void* d_out, int out_size, void* d_ws, size_t ws_size,
                              hipStream_t stream) {
    const float* qh    = (const float*)d_in[0];
    const float* dh    = (const float*)d_in[1];
    const float* W     = (const float*)d_in[2];
    const int*   dmask = (const int*)d_in[3];
    const int*   ppq   = (const int*)d_in[4];
    float*       out   = (float*)d_out;

    unsigned short* wsW  = (unsigned short*)d_ws;                      // 384 KB
    unsigned short* qn   = (unsigned short*)((char*)d_ws + 393216);    // 256 KB
    // WT (384 KB, qproj-only) and part (512 KB, written after qproj) overlay:
    float*          WT   = (float*)((char*)d_ws + 655360);
    float*          part = (float*)((char*)d_ws + 655360);

    const int nq = in_sizes[0] / H;      // 1024 query tokens
    const int Bd = out_size;             // 256 docs

    wconv_kernel<<<NT, 256, 0, stream>>>(W, wsW, WT);
    qproj_kernel<<<nq / 4, 128, 0, stream>>>(qh, WT, qn);
    docgemm_kernel<<<Bd * 16, 256, 0, stream>>>(dh, wsW, dmask, qn, part, ppq);
    final_kernel<<<Bd, 64, 0, stream>>>(part, out);
}

// Round 10
// 131.536 us; speedup vs baseline: 2.3410x; 2.3410x over previous
//
#include <hip/hip_runtime.h>
#include <math.h>

#define H    768
#define NT   24           // H/32 K-tiles
#define DIM  128
#define LQ   32
#define LD   512
#define BM   128          // tokens per block
#define EPSF 1e-12f

typedef _Float16 f16x8 __attribute__((ext_vector_type(8)));
typedef _Float16 f16x4 __attribute__((ext_vector_type(4)));
typedef float    f32x4 __attribute__((ext_vector_type(4)));

static __device__ __forceinline__ unsigned short h2u(_Float16 h) {
    return __builtin_bit_cast(unsigned short, h);
}

#define GLOAD_LDS16(g, l) __builtin_amdgcn_global_load_lds(                    \
    (const __attribute__((address_space(1))) unsigned int*)(const void*)(g),   \
    (__attribute__((address_space(3))) unsigned int*)(void*)(l), 16, 0, 0)

// ------- W -> single f16 (pre-swizzled, for docgemm) + WT fp32 (qproj) -------
// wsW layout: [ks][row=dim 0..127][32 cols swizzled]  (8 KB per K-tile)
__global__ __launch_bounds__(256) void wconv_kernel(
    const float* __restrict__ W, unsigned short* __restrict__ wsW,
    float* __restrict__ WT)
{
    const int ks  = blockIdx.x;
    const int tid = threadIdx.x;
    #pragma unroll 4
    for (int i = 0; i < 16; ++i) {
        const int idx = tid + i * 256;          // 0..4095
        const int row = idx >> 5, col = idx & 31;
        const float x = W[(size_t)row * H + ks * 32 + col];
        const int colS = (((col >> 3) ^ ((row >> 1) & 3)) << 3) | (col & 7);
        wsW[((size_t)ks * 128 + row) * 32 + colS] = h2u((_Float16)x);
        WT[((size_t)ks * 32 + col) * DIM + row] = x;
    }
}

// ---------------- query projection (coalesced via WT) + L2 norm -> f16 -------
__global__ __launch_bounds__(128) void qproj_kernel(
    const float* __restrict__ qh, const float* __restrict__ WT,
    unsigned short* __restrict__ qn)
{
    const int blk = blockIdx.x;   // 4 tokens per block
    const int tid = threadIdx.x;  // = output dim
    __shared__ float rows[4][H];
    __shared__ float red[128];

    const float4* src = (const float4*)(qh + (size_t)blk * 4 * H);
    float4*       dst = (float4*)&rows[0][0];
    for (int i = tid; i < 4 * H / 4; i += 128) dst[i] = src[i];
    __syncthreads();

    float acc[4] = {0.f, 0.f, 0.f, 0.f};
    #pragma unroll 8
    for (int h = 0; h < H; ++h) {
        const float wv = WT[(size_t)h * DIM + tid];   // coalesced across lanes
        acc[0] += wv * rows[0][h];
        acc[1] += wv * rows[1][h];
        acc[2] += wv * rows[2][h];
        acc[3] += wv * rows[3][h];
    }
    #pragma unroll
    for (int j = 0; j < 4; ++j) {
        red[tid] = acc[j] * acc[j];
        __syncthreads();
        for (int s = 64; s > 0; s >>= 1) {
            if (tid < s) red[tid] += red[tid + s];
            __syncthreads();
        }
        const float inv = 1.0f / fmaxf(sqrtf(red[0]), EPSF);
        qn[((size_t)blk * 4 + j) * DIM + tid] = h2u((_Float16)(acc[j] * inv));
        __syncthreads();
    }
}

// -------- doc: R4-style pipelined f16 MFMA, single-W, BM=128, 4 waves --------
struct Smem {
    union {
        struct {  // GEMM stage: 16 KB A + 16 KB W
            unsigned short A[2][BM][32];
            unsigned short Wt[2][128][32];
        } g;
        unsigned short C[BM][DIM];   // epilogue: 32 KB (overlays GEMM region)
    } u;
    float         pnorm[2][BM];      // 1 KB
    unsigned char mk[BM];            // 128 B
    float         pmax[LQ][4];       // 512 B
};

__global__ __launch_bounds__(256, 4) void docgemm_kernel(
    const float* __restrict__ dh, const unsigned short* __restrict__ wsW,
    const int* __restrict__ dmask, const unsigned short* __restrict__ qn,
    float* __restrict__ part, const int* __restrict__ ppq_p)
{
    __shared__ Smem sm;
    const int blk = blockIdx.x;      // 1024 blocks
    const int b   = blk >> 2;        // doc
    const int c   = blk & 3;         // 128-token chunk
    const int tid = threadIdx.x;
    const int w   = tid >> 6;        // wave 0..3
    const int wm  = w >> 1, wn = w & 1;   // 2 token-tiles x 2 dim-halves
    const int l   = tid & 63;
    const int g   = l >> 4;
    const int r15 = l & 15;
    const int ppq = ppq_p[0];

    // A staging geometry: thread -> rows r0 + i*32 (i=0..3), float4 segment seg0
    const int r0   = tid >> 3;       // 0..31
    const int seg0 = tid & 7;        // 0..7
    const int aswz = (r0 >> 1) & 3;  // invariant under +32 row steps
    const int coli = (((seg0 >> 1) ^ aswz) << 3) | ((seg0 & 1) << 2);

    const float* Abase = dh + ((size_t)b * LD + (size_t)c * BM) * H;

    f32x4 acc[4][4];
    #pragma unroll
    for (int m = 0; m < 4; ++m)
        #pragma unroll
        for (int n = 0; n < 4; ++n)
            acc[m][n] = (f32x4){0.f, 0.f, 0.f, 0.f};

    float4 avA[4];

    // ---- prologue: W(0) (oldest), A(0) -> convert, A(1) left in flight ----
    {
        const char* wt   = (const char*)wsW;
        char*       wdst = (char*)&sm.u.g.Wt[0][0][0];
        GLOAD_LDS16(wt + tid * 16,        wdst + w * 1024);
        GLOAD_LDS16(wt + 4096 + tid * 16, wdst + 4096 + w * 1024);
        __builtin_amdgcn_sched_barrier(0);
        #pragma unroll
        for (int i = 0; i < 4; ++i)
            avA[i] = *(const float4*)(Abase + (size_t)(r0 + i * 32) * H + seg0 * 4);
        #pragma unroll
        for (int i = 0; i < 4; ++i) {
            const int row = r0 + i * 32;
            f16x4 h;
            h[0] = (_Float16)avA[i].x; h[1] = (_Float16)avA[i].y;
            h[2] = (_Float16)avA[i].z; h[3] = (_Float16)avA[i].w;
            *(f16x4*)&sm.u.g.A[0][row][coli] = h;
        }
        #pragma unroll
        for (int i = 0; i < 4; ++i)
            avA[i] = *(const float4*)(Abase + (size_t)(r0 + i * 32) * H + 32 + seg0 * 4);
        asm volatile("s_waitcnt vmcnt(4) lgkmcnt(0)" ::: "memory");
        __builtin_amdgcn_sched_barrier(0);
        __builtin_amdgcn_s_barrier();
        __builtin_amdgcn_sched_barrier(0);
    }

    // ---- main K-loop: counted vmcnt keeps A(t+2) in flight across barrier ----
    for (int t = 0; t < NT; ++t) {
        const int cur = t & 1, nxt = cur ^ 1;

        if (t + 1 < NT) {  // W(t+1) via global_load_lds — issued FIRST (oldest)
            const char* wt   = (const char*)wsW + (size_t)(t + 1) * 8192;
            char*       wdst = (char*)&sm.u.g.Wt[nxt][0][0];
            GLOAD_LDS16(wt + tid * 16,        wdst + w * 1024);
            GLOAD_LDS16(wt + 4096 + tid * 16, wdst + 4096 + w * 1024);
        }
        __builtin_amdgcn_sched_barrier(0);   // pin: W issue precedes the rest

        f16x8 ah[4];
        #pragma unroll
        for (int m = 0; m < 4; ++m) {
            const int row = wm * 64 + m * 16 + r15;
            const int sl  = (g ^ ((row >> 1) & 3)) * 8;
            ah[m] = *(const f16x8*)&sm.u.g.A[cur][row][sl];
        }
        __builtin_amdgcn_s_setprio(1);
        #pragma unroll
        for (int n = 0; n < 4; ++n) {
            const int row = wn * 64 + n * 16 + r15;
            const int sl  = (g ^ ((row >> 1) & 3)) * 8;
            f16x8 bh = *(const f16x8*)&sm.u.g.Wt[cur][row][sl];
            #pragma unroll
            for (int m = 0; m < 4; ++m)
                acc[m][n] = __builtin_amdgcn_mfma_f32_16x16x32_f16(ah[m], bh, acc[m][n], 0, 0, 0);
        }
        __builtin_amdgcn_s_setprio(0);

        if (t + 1 < NT) {  // convert avA (tile t+1 data) -> LDS buf[nxt]
            #pragma unroll
            for (int i = 0; i < 4; ++i) {
                const int row = r0 + i * 32;
                f16x4 h;
                h[0] = (_Float16)avA[i].x; h[1] = (_Float16)avA[i].y;
                h[2] = (_Float16)avA[i].z; h[3] = (_Float16)avA[i].w;
                *(f16x4*)&sm.u.g.A[nxt][row][coli] = h;
            }
        }
        if (t + 2 < NT) {  // issue A(t+2) — youngest, allowed to stay in flight
            const int k0n = (t + 2) * 32;
            #pragma unroll
            for (int i = 0; i < 4; ++i)
                avA[i] = *(const float4*)(Abase + (size_t)(r0 + i * 32) * H + k0n + seg0 * 4);
        }

        if (t + 2 < NT) {
            asm volatile("s_waitcnt vmcnt(4) lgkmcnt(0)" ::: "memory");
        } else {
            asm volatile("s_waitcnt vmcnt(0) lgkmcnt(0)" ::: "memory");
        }
        __builtin_amdgcn_sched_barrier(0);
        __builtin_amdgcn_s_barrier();
        __builtin_amdgcn_sched_barrier(0);
    }

    // ---- epilogue 1: C -> LDS f16 (swizzled), per-token norms from registers
    #pragma unroll
    for (int m = 0; m < 4; ++m) {
        const int tokb = wm * 64 + m * 16 + g * 4;
        #pragma unroll
        for (int n = 0; n < 4; ++n) {
            const int dim = wn * 64 + n * 16 + r15;
            #pragma unroll
            for (int r = 0; r < 4; ++r) {
                const int tok  = tokb + r;
                const int slot = (dim >> 3) ^ (tok & 7);
                sm.u.C[tok][slot * 8 + (dim & 7)] = h2u((_Float16)acc[m][n][r]);
            }
        }
    }
    #pragma unroll
    for (int m = 0; m < 4; ++m) {
        #pragma unroll
        for (int r = 0; r < 4; ++r) {
            float s = 0.f;
            #pragma unroll
            for (int n = 0; n < 4; ++n) s += acc[m][n][r] * acc[m][n][r];
            s += __shfl_xor(s, 1); s += __shfl_xor(s, 2);
            s += __shfl_xor(s, 4); s += __shfl_xor(s, 8);
            if (r15 == 0) sm.pnorm[wn][wm * 64 + m * 16 + g * 4 + r] = s;
        }
    }
    if (tid < BM) sm.mk[tid] = (unsigned char)(dmask[(size_t)b * LD + c * BM + tid] != 0);
    __syncthreads();

    // ---- epilogue 2: sim GEMM [32 q] x [32 tokens per wave], K=128 ----
    const unsigned short* qb = qn + (size_t)(b / ppq) * LQ * DIM;
    const int t0 = w * 32 + r15, t1 = t0 + 16;
    const float inv0 = 1.0f / fmaxf(sqrtf(sm.pnorm[0][t0] + sm.pnorm[1][t0]), EPSF);
    const float inv1 = 1.0f / fmaxf(sqrtf(sm.pnorm[0][t1] + sm.pnorm[1][t1]), EPSF);

    f32x4 sacc[2][2];
    #pragma unroll
    for (int m = 0; m < 2; ++m)
        #pragma unroll
        for (int n = 0; n < 2; ++n)
            sacc[m][n] = (f32x4){0.f, 0.f, 0.f, 0.f};
    #pragma unroll
    for (int ks = 0; ks < 4; ++ks) {
        f16x8 qa[2], cb[2];
        #pragma unroll
        for (int m = 0; m < 2; ++m)
            qa[m] = *(const f16x8*)(qb + (size_t)(m * 16 + r15) * DIM + ks * 32 + g * 8);
        #pragma unroll
        for (int n = 0; n < 2; ++n) {
            const int row  = w * 32 + n * 16 + r15;
            const int slot = (ks * 4 + g) ^ (row & 7);
            cb[n] = *(const f16x8*)&sm.u.C[row][slot * 8];
        }
        #pragma unroll
        for (int m = 0; m < 2; ++m)
            #pragma unroll
            for (int n = 0; n < 2; ++n)
                sacc[m][n] = __builtin_amdgcn_mfma_f32_16x16x32_f16(qa[m], cb[n], sacc[m][n], 0, 0, 0);
    }

    // ---- masked per-query max over this wave's 32 tokens ----
    const int m0 = sm.mk[t0], m1 = sm.mk[t1];
    #pragma unroll
    for (int m = 0; m < 2; ++m) {
        #pragma unroll
        for (int r = 0; r < 4; ++r) {
            float v0 = m0 ? sacc[m][0][r] * inv0 : -INFINITY;
            float v1 = m1 ? sacc[m][1][r] * inv1 : -INFINITY;
            float vmax = fmaxf(v0, v1);
            vmax = fmaxf(vmax, __shfl_xor(vmax, 1));
            vmax = fmaxf(vmax, __shfl_xor(vmax, 2));
            vmax = fmaxf(vmax, __shfl_xor(vmax, 4));
            vmax = fmaxf(vmax, __shfl_xor(vmax, 8));
            if (r15 == 0) sm.pmax[m * 16 + g * 4 + r][w] = vmax;
        }
    }
    __syncthreads();
    if (tid < LQ) {
        float mv = fmaxf(fmaxf(sm.pmax[tid][0], sm.pmax[tid][1]),
                         fmaxf(sm.pmax[tid][2], sm.pmax[tid][3]));
        part[(size_t)blk * 32 + tid] = mv;
    }
}

// ---------------- final: max over 4 chunks, sum over queries ----------------
__global__ __launch_bounds__(64) void final_kernel(
    const float* __restrict__ part, float* __restrict__ out)
{
    const int b = blockIdx.x;
    const int q = threadIdx.x & 31;
    const float* p = part + (size_t)b * 128;
    float m = fmaxf(fmaxf(p[q], p[32 + q]), fmaxf(p[64 + q], p[96 + q]));
    #pragma unroll
    for (int off = 1; off < 32; off <<= 1) m += __shfl_xor(m, off);
    if (threadIdx.x == 0) out[b] = m;
}

extern "C" void kernel_launch(void* const* d_in, const int* in_sizes, int n_in,
                              void* d_out, int out_size, void* d_ws, size_t ws_size,
                              hipStream_t stream) {
    const float* qh    = (const float*)d_in[0];
    const float* dh    = (const float*)d_in[1];
    const float* W     = (const float*)d_in[2];
    const int*   dmask = (const int*)d_in[3];
    const int*   ppq   = (const int*)d_in[4];
    float*       out   = (float*)d_out;

    unsigned short* wsW  = (unsigned short*)d_ws;                      // 192 KB
    float*          WT   = (float*)((char*)d_ws + 196608);             // 384 KB
    unsigned short* qn   = (unsigned short*)((char*)d_ws + 589824);    // 256 KB
    float*          part = (float*)((char*)d_ws + 851968);             // 128 KB

    const int nq = in_sizes[0] / H;      // 1024 query tokens
    const int Bd = out_size;             // 256 docs

    wconv_kernel<<<NT, 256, 0, stream>>>(W, wsW, WT);
    qproj_kernel<<<nq / 4, 128, 0, stream>>>(qh, WT, qn);
    docgemm_kernel<<<Bd * 4, 256, 0, stream>>>(dh, wsW, dmask, qn, part, ppq);
    final_kernel<<<Bd, 64, 0, stream>>>(part, out);
}